// Round 9
// baseline (142.312 us; speedup 1.0000x reference)
//
#include <hip/hip_runtime.h>
#include <hip/hip_bf16.h>

// Modulated conv2d (StyleGAN2) on MI355X.
// out[b,o] = rsig[b,o] * conv(s[b,:]*x[b,:], W*SCALE)   (shared weights)
// rsig[b,o] = 1/sqrt(sum_i s[b,i]^2 * wsq[o,i] + 1e-8)
// Conv as implicit GEMM: D[o][p] = sum_k Wb[o][k] * Xcl[p][k].
//
// R9: R6 structure (z-split K, 512 blocks = 2/CU, 256 thr, 4 waves 2Mx2N,
// per-wave 64x128, single-buffer 48KB, 2x __syncthreads) with:
//  (1) mfma_f32_32x32x16 (8.07 vs 9.7 cyc/32KFLOP; half the instructions);
//  (2) FRAGMENT-MAJOR LDS layout [frag][lane][16B] -> every ds_read_b128 is
//      lane-contiguous (0 conflicts, no swizzle); gather done by per-lane
//      global source addresses of gload_lds (dest stays linear, rule 21 ok);
//  (3) both z-halves write bf16 partials; merge out = p0+p1 (conv writes
//      84->34MB, merge 151->100MB); ws-size fallback to R6 scheme;
//  (4) halo-only zero kernel replaces the 19MB memset.
// Model: serial-sum/CU = MFMA 74.4K + reads 54K + writes ~20K ~= 150K cyc.

typedef __attribute__((ext_vector_type(4))) float f32x4;
typedef __attribute__((ext_vector_type(16))) float f32x16;
typedef __attribute__((ext_vector_type(8))) short bf16x8;

#define NB    16
#define CIN   512
#define COUT  512
#define KTOT  4608           // CIN * 9
#define NPIX  (NB * 32 * 32) // 16384

__device__ __forceinline__ void gload_lds16(const void* g, void* l) {
  __builtin_amdgcn_global_load_lds(
      (__attribute__((address_space(1))) void*)(g),
      (__attribute__((address_space(3))) void*)(l), 16, 0, 0);
}

__device__ __forceinline__ float bf16bits_to_f32(short v) {
  return __uint_as_float(((unsigned)(unsigned short)v) << 16);
}

// ---- kernel 1: pack weights (bf16, [o][tap*512+ci]) + wsq ----
__global__ __launch_bounds__(256) void pack_w_kernel(
    const float* __restrict__ w, __hip_bfloat16* __restrict__ wB,
    float* __restrict__ wsq) {
  const int idx = blockIdx.x * 256 + threadIdx.x;   // = o*512 + ci
  const int o = idx >> 9, ci = idx & 511;
  const float* wp = w + (size_t)idx * 9;
  const float WSCALE = 0.014731391274719739f;       // 1/sqrt(512*9)
  float sum = 0.f;
#pragma unroll
  for (int t = 0; t < 9; ++t) {
    float v = wp[t] * WSCALE;
    sum += v * v;
    wB[(size_t)o * KTOT + t * 512 + ci] = __float2bfloat16(v);
  }
  wsq[idx] = sum;
}

// ---- kernel 2: rsig[b][o], one wave per (b,o) ----
__global__ __launch_bounds__(256) void calc_rsig_kernel(
    const float* __restrict__ s, const float* __restrict__ wsq,
    float* __restrict__ rsig) {
  const int wid = blockIdx.x * 4 + (threadIdx.x >> 6); // b*512 + o
  const int lane = threadIdx.x & 63;
  const int b = wid >> 9, o = wid & 511;
  const float* sp = s + b * 512;
  const float* wp = wsq + o * 512;
  float sum = 0.f;
#pragma unroll
  for (int i = 0; i < 8; ++i) {
    float sv = sp[lane + i * 64];
    sum += sv * sv * wp[lane + i * 64];
  }
#pragma unroll
  for (int off = 32; off > 0; off >>= 1) sum += __shfl_down(sum, off, 64);
  if (lane == 0) rsig[wid] = 1.0f / sqrtf(sum + 1e-8f);
}

// ---- kernel 3: modulate + NCHW -> padded channels-last bf16 ----
__global__ __launch_bounds__(256) void modulate_kernel(
    const float* __restrict__ x, const float* __restrict__ s,
    __hip_bfloat16* __restrict__ xpad) {
  const int by = blockIdx.x;            // b*32 + y
  const int b = by >> 5, y = by & 31;
  __shared__ __attribute__((aligned(16))) __hip_bfloat16 tile[32][72];
  const int tid = threadIdx.x;
  const int xc = tid & 31;
  const int cr0 = tid >> 5;
  const float* xrow = x + ((size_t)b * 512 * 32 + y) * 32;
  const float* sb = s + b * 512;
  __hip_bfloat16* orow = xpad + (size_t)((b * 34 + y + 1) * 34) * 512;

  for (int ci0 = 0; ci0 < 512; ci0 += 64) {
#pragma unroll
    for (int r = 0; r < 8; ++r) {
      const int cir = r * 8 + cr0;
      const int ci = ci0 + cir;
      float v = xrow[(size_t)ci * 1024 + xc] * sb[ci];
      tile[xc][cir] = __float2bfloat16(v);
    }
    __syncthreads();
    const int xcw = tid >> 3, vec = tid & 7;
    bf16x8 v = *(const bf16x8*)&tile[xcw][vec * 8];
    *(bf16x8*)(orow + (size_t)(xcw + 1) * 512 + ci0 + vec * 8) = v;
    __syncthreads();
  }
}

// ---- kernel 3b: zero only the halo of xpad (replaces 19MB memset) ----
__global__ __launch_bounds__(256) void halo_zero_kernel(
    __hip_bfloat16* __restrict__ xpad) {
  const int sb = blockIdx.x;           // b*132 + site
  const int b = sb / 132, s = sb - b * 132;
  int y, x;
  if (s < 34)       { y = 0;        x = s; }
  else if (s < 68)  { y = 33;       x = s - 34; }
  else if (s < 100) { y = s - 67;   x = 0; }    // y = (s-68)+1
  else              { y = s - 99;   x = 33; }   // y = (s-100)+1
  unsigned* p = (unsigned*)(xpad + (size_t)((b * 34 + y) * 34 + x) * 512);
  p[threadIdx.x] = 0u;   // 256 x 4B = 512 bf16
}

// ---- kernel 4: implicit-GEMM conv, 32x32x16 MFMA, fragment-major LDS ----
// Block: 128 cout x 256 pix x K2304 (z in {0,1}; 36 K64-tiles). 4 waves 2Mx2N,
// per-wave 64x128 = 2x4 frags of 32x32. LDS 48KB: A frag-major 16KB
// ([fi*4+ks][lane][16B], fi=row/32, ks=k/16), then B frag-major 32KB
// ([ni*4+ks][lane][16B], ni=pix/32). A-operand lane l: row=l&31,
// k=(l>>5)*8+j; B-operand: col=l&31, k=(l>>5)*8+j; C/D: col=lane&31,
// row=(reg&3)+8*(reg>>2)+4*(lane>>5)  [guide-verified m74/m101].
__global__ __launch_bounds__(256, 2) void conv_gemm_kernel(
    const __hip_bfloat16* __restrict__ wB,    // [512][4608]
    const __hip_bfloat16* __restrict__ xpad,  // [16][34][34][512]
    const float* __restrict__ rsig,           // [16][512]
    float* __restrict__ out,                  // f32 out (fallback path, z=0)
    __hip_bfloat16* __restrict__ p0,          // bf16 partial z=0 (or null)
    __hip_bfloat16* __restrict__ p1) {        // bf16 partial z=1
  __shared__ __attribute__((aligned(16))) char ldsc[49152];

  const int tid = threadIdx.x;
  const int wv = tid >> 6, lane = tid & 63;
  const int l31 = lane & 31, lhi = lane >> 5;
  const int bo0 = blockIdx.y << 7;   // cout block (128)
  const int bp0 = blockIdx.x << 8;   // pixel block (256; 256 | 1024 per image)
  const int z = blockIdx.z;          // K-half
  const int bimg = blockIdx.x >> 2;
  const int wr = wv >> 1, wc = wv & 1;

  // Staging source offsets: invert the fragment-major dest layout.
  // dest unit u = r*256+tid (16B units); frag = u>>6, l = u&63.
  int gA[4];   // + ktg*64 per tile
#pragma unroll
  for (int r = 0; r < 4; ++r) {
    const int u = r * 256 + tid, frag = u >> 6, l = u & 63;
    const int fi = frag >> 2, ks = frag & 3;
    const int row = fi * 32 + (l & 31), k = ks * 16 + (l >> 5) * 8;
    gA[r] = (bo0 + row) * KTOT + k;
  }
  int gB[8];   // + xoff per tile
#pragma unroll
  for (int r = 0; r < 8; ++r) {
    const int u = r * 256 + tid, frag = u >> 6, l = u & 63;
    const int ni = frag >> 2, ks = frag & 3;
    const int pr = ni * 32 + (l & 31), k = ks * 16 + (l >> 5) * 8;
    const int p = bp0 + pr, b = p >> 10, rem = p & 1023, y = rem >> 5,
              xx = rem & 31;
    gB[r] = ((b * 34 + y) * 34 + xx) * 512 + k;
  }

  f32x16 acc[2][4];
#pragma unroll
  for (int mi = 0; mi < 2; ++mi)
#pragma unroll
    for (int ni = 0; ni < 4; ++ni)
#pragma unroll
      for (int e = 0; e < 16; ++e) acc[mi][ni][e] = 0.f;

#pragma unroll 1
  for (int kt = 0; kt < 36; ++kt) {
    const int ktg = z * 36 + kt;
    const int tap = ktg >> 3;
    const int xoff = (tap + 31 * (tap / 3)) * 512 + ((ktg & 7) << 6);
#pragma unroll
    for (int r = 0; r < 4; ++r)
      gload_lds16(wB + (size_t)(gA[r] + (ktg << 6)),
                  ldsc + (r * 256 + tid) * 16);
#pragma unroll
    for (int r = 0; r < 8; ++r)
      gload_lds16(xpad + (size_t)(gB[r] + xoff),
                  ldsc + 16384 + (r * 256 + tid) * 16);
    __syncthreads();   // drains vmcnt -> staged data visible

    bf16x8 av[2][4];
#pragma unroll
    for (int mi = 0; mi < 2; ++mi)
#pragma unroll
      for (int ks = 0; ks < 4; ++ks)
        av[mi][ks] = *(const bf16x8*)(
            ldsc + (((wr * 2 + mi) * 4 + ks) << 10) + lane * 16);
#pragma unroll
    for (int ks = 0; ks < 4; ++ks) {
      bf16x8 bv[4];
#pragma unroll
      for (int ni = 0; ni < 4; ++ni)
        bv[ni] = *(const bf16x8*)(
            ldsc + 16384 + (((wc * 4 + ni) * 4 + ks) << 10) + lane * 16);
#pragma unroll
      for (int mi = 0; mi < 2; ++mi)
#pragma unroll
        for (int ni = 0; ni < 4; ++ni)
          acc[mi][ni] = __builtin_amdgcn_mfma_f32_32x32x16_bf16(
              av[mi][ks], bv[ni], acc[mi][ni], 0, 0, 0);
    }
    __syncthreads();   // all reads done before next stage overwrites
  }

  // Epilogue. D row = (reg&3) + 8*(reg>>2) + 4*(lane>>5), col = lane&31.
  __hip_bfloat16* pz = z ? p1 : p0;
  const bool f32path = (p0 == nullptr) && (z == 0);
#pragma unroll
  for (int mi = 0; mi < 2; ++mi) {
    const int obase = bo0 + (wr << 6) + (mi << 5);
#pragma unroll
    for (int q = 0; q < 4; ++q) {
      const int r4 = q * 8 + lhi * 4;
      const f32x4 rs = *(const f32x4*)(rsig + (bimg << 9) + obase + r4);
#pragma unroll
      for (int ni = 0; ni < 4; ++ni) {
        const int p = bp0 + (wc << 7) + (ni << 5) + l31;
        const int prem = p & 1023;
#pragma unroll
        for (int j = 0; j < 4; ++j) {
          const float v = acc[mi][ni][q * 4 + j] * rs[j];
          const size_t oidx =
              ((size_t)((bimg << 9) + obase + r4 + j)) * 1024 + prem;
          if (f32path) out[oidx] = v;
          else pz[oidx] = __float2bfloat16(v);
        }
      }
    }
  }
}

// ---- kernel 5a: merge out = p0 + p1 (8 elems/thread) ----
__global__ __launch_bounds__(256) void merge2_kernel(
    float* __restrict__ out, const __hip_bfloat16* __restrict__ p0,
    const __hip_bfloat16* __restrict__ p1) {
  const size_t i = (size_t)blockIdx.x * 256 + threadIdx.x;
  const bf16x8 a = ((const bf16x8*)p0)[i];
  const bf16x8 b = ((const bf16x8*)p1)[i];
  f32x4 o0, o1;
#pragma unroll
  for (int j = 0; j < 4; ++j) {
    o0[j] = bf16bits_to_f32(a[j]) + bf16bits_to_f32(b[j]);
    o1[j] = bf16bits_to_f32(a[4 + j]) + bf16bits_to_f32(b[4 + j]);
  }
  ((f32x4*)out)[2 * i] = o0;
  ((f32x4*)out)[2 * i + 1] = o1;
}

// ---- kernel 5b: fallback merge out += p1 ----
__global__ __launch_bounds__(256) void merge1_kernel(
    float* __restrict__ out, const __hip_bfloat16* __restrict__ p1) {
  const size_t i = (size_t)blockIdx.x * 256 + threadIdx.x;
  f32x4* o4 = (f32x4*)out + 2 * i;
  f32x4 a = o4[0], b = o4[1];
  const bf16x8 pv = ((const bf16x8*)p1)[i];
#pragma unroll
  for (int j = 0; j < 4; ++j) {
    a[j] += bf16bits_to_f32(pv[j]);
    b[j] += bf16bits_to_f32(pv[4 + j]);
  }
  o4[0] = a;
  o4[1] = b;
}

extern "C" void kernel_launch(void* const* d_in, const int* in_sizes, int n_in,
                              void* d_out, int out_size, void* d_ws,
                              size_t ws_size, hipStream_t stream) {
  const float* x = (const float*)d_in[0];   // [16,512,32,32]
  const float* s = (const float*)d_in[1];   // [16,512]
  const float* w = (const float*)d_in[2];   // [512,512,3,3]
  float* out = (float*)d_out;               // [16,512,32,32] f32

  char* ws = (char*)d_ws;
  const size_t xpad_bytes = (size_t)NB * 34 * 34 * 512 * 2;  // 18,939,904
  const size_t wB_bytes = (size_t)COUT * KTOT * 2;           //  4,718,592
  const size_t wsq_bytes = (size_t)COUT * CIN * 4;           //  1,048,576
  const size_t rsig_bytes = (size_t)NB * COUT * 4;           //     32,768
  const size_t part_bytes = (size_t)NPIX * COUT * 2;         // 16,777,216
  __hip_bfloat16* xpad = (__hip_bfloat16*)ws;
  __hip_bfloat16* wB = (__hip_bfloat16*)(ws + xpad_bytes);
  float* wsq = (float*)(ws + xpad_bytes + wB_bytes);
  float* rsig = (float*)(ws + xpad_bytes + wB_bytes + wsq_bytes);
  char* pbase = ws + xpad_bytes + wB_bytes + wsq_bytes + rsig_bytes;
  __hip_bfloat16* p1 = (__hip_bfloat16*)pbase;
  __hip_bfloat16* p0 = (__hip_bfloat16*)(pbase + part_bytes);
  const bool two_partials =
      ws_size >= (xpad_bytes + wB_bytes + wsq_bytes + rsig_bytes +
                  2 * part_bytes);

  halo_zero_kernel<<<NB * 132, 256, 0, stream>>>(xpad);
  pack_w_kernel<<<(COUT * CIN) / 256, 256, 0, stream>>>(w, wB, wsq);
  modulate_kernel<<<NB * 32, 256, 0, stream>>>(x, s, xpad);
  calc_rsig_kernel<<<(NB * COUT) / 4, 256, 0, stream>>>(s, wsq, rsig);
  conv_gemm_kernel<<<dim3(NPIX / 256, COUT / 128, 2), 256, 0, stream>>>(
      wB, xpad, rsig, out, two_partials ? p0 : nullptr, p1);
  const int mblocks = (NPIX * COUT / 8) / 256;   // 4096
  if (two_partials)
    merge2_kernel<<<mblocks, 256, 0, stream>>>(out, p0, p1);
  else
    merge1_kernel<<<mblocks, 256, 0, stream>>>(out, p1);
}

// Round 10
// 102.388 us; speedup vs baseline: 1.3899x; 1.3899x over previous
//
#include <hip/hip_runtime.h>
#include <hip/hip_bf16.h>

// Modulated conv2d (StyleGAN2) on MI355X.
// out[b,o] = rsig[b,o] * conv(s[b,:]*x[b,:], W*SCALE)   (shared weights)
// rsig[b,o] = 1/sqrt(sum_i s[b,i]^2 * wsq[o,i] + 1e-8)
// Conv as implicit GEMM: D[o][p] = sum_k Wb[o][k] * Xcl[p][k].
//
// R10 = R6 structure (z-split K by ci, 512 blocks = 2/CU, 256 thr, 4 waves
// 2Mx2N, per-wave 64x128, 16x16x32 MFMA, row-major LDS + XOR swizzle,
// coalesced 128B staging) with:
//  (1) tap-superset B staging: per ci-group stage the 10x34-row x 64-ci xpad
//      slice ONCE (44KB serves 9 taps) -> B LDS-writes 32KB/tile -> 4.9KB/tile
//      (write term 27K -> 13K cyc/CU). Addressing = R5's verified code
//      (R5's failure was a launch_bounds(512,2) VGPR spill, not the layout).
//  (2) A double-buffered (2x16KB), prefetch distance 1, uniform vmcnt(0)+BAR
//      per tile; B(g+1) staged under tap-8 MFMAs behind a mid-tile barrier.
//  (3) bf16 partials for BOTH z-halves + merge2 (151->100MB tail traffic),
//      halo-only zero instead of 19MB memset (R9-verified pieces).

typedef __attribute__((ext_vector_type(4))) float f32x4;
typedef __attribute__((ext_vector_type(8))) short bf16x8;

#define NB    16
#define CIN   512
#define COUT  512
#define KTOT  4608           // CIN * 9
#define NPIX  (NB * 32 * 32) // 16384

#define WAITV0() asm volatile("s_waitcnt vmcnt(0)" ::: "memory")
#define FENCE()  asm volatile("" ::: "memory")
#define BAR()    { FENCE(); __builtin_amdgcn_s_barrier(); FENCE(); }

__device__ __forceinline__ void gload_lds16(const void* g, void* l) {
  __builtin_amdgcn_global_load_lds(
      (__attribute__((address_space(1))) void*)(g),
      (__attribute__((address_space(3))) void*)(l), 16, 0, 0);
}

__device__ __forceinline__ float bf16bits_to_f32(short v) {
  return __uint_as_float(((unsigned)(unsigned short)v) << 16);
}

// ---- kernel 1: pack weights as wB3[o][(ci>>6)*9+tap][ci&63] bf16 + wsq ----
// -> each K64-tile kt = g_abs*9+tap is a contiguous 128B row per o.
__global__ __launch_bounds__(256) void pack_w_kernel(
    const float* __restrict__ w, __hip_bfloat16* __restrict__ wB3,
    float* __restrict__ wsq) {
  const int idx = blockIdx.x * 256 + threadIdx.x;   // = o*512 + ci
  const int o = idx >> 9, ci = idx & 511;
  const float* wp = w + (size_t)idx * 9;
  const float WSCALE = 0.014731391274719739f;       // 1/sqrt(512*9)
  float sum = 0.f;
#pragma unroll
  for (int t = 0; t < 9; ++t) {
    float v = wp[t] * WSCALE;
    sum += v * v;
    wB3[(size_t)o * KTOT + (((ci >> 6) * 9 + t) << 6) + (ci & 63)] =
        __float2bfloat16(v);
  }
  wsq[idx] = sum;
}

// ---- kernel 2: rsig[b][o], one wave per (b,o) ----
__global__ __launch_bounds__(256) void calc_rsig_kernel(
    const float* __restrict__ s, const float* __restrict__ wsq,
    float* __restrict__ rsig) {
  const int wid = blockIdx.x * 4 + (threadIdx.x >> 6); // b*512 + o
  const int lane = threadIdx.x & 63;
  const int b = wid >> 9, o = wid & 511;
  const float* sp = s + b * 512;
  const float* wp = wsq + o * 512;
  float sum = 0.f;
#pragma unroll
  for (int i = 0; i < 8; ++i) {
    float sv = sp[lane + i * 64];
    sum += sv * sv * wp[lane + i * 64];
  }
#pragma unroll
  for (int off = 32; off > 0; off >>= 1) sum += __shfl_down(sum, off, 64);
  if (lane == 0) rsig[wid] = 1.0f / sqrtf(sum + 1e-8f);
}

// ---- kernel 3: modulate + NCHW -> padded channels-last bf16 ----
__global__ __launch_bounds__(256) void modulate_kernel(
    const float* __restrict__ x, const float* __restrict__ s,
    __hip_bfloat16* __restrict__ xpad) {
  const int by = blockIdx.x;            // b*32 + y
  const int b = by >> 5, y = by & 31;
  __shared__ __attribute__((aligned(16))) __hip_bfloat16 tile[32][72];
  const int tid = threadIdx.x;
  const int xc = tid & 31;
  const int cr0 = tid >> 5;
  const float* xrow = x + ((size_t)b * 512 * 32 + y) * 32;
  const float* sb = s + b * 512;
  __hip_bfloat16* orow = xpad + (size_t)((b * 34 + y + 1) * 34) * 512;

  for (int ci0 = 0; ci0 < 512; ci0 += 64) {
#pragma unroll
    for (int r = 0; r < 8; ++r) {
      const int cir = r * 8 + cr0;
      const int ci = ci0 + cir;
      float v = xrow[(size_t)ci * 1024 + xc] * sb[ci];
      tile[xc][cir] = __float2bfloat16(v);
    }
    __syncthreads();
    const int xcw = tid >> 3, vec = tid & 7;
    bf16x8 v = *(const bf16x8*)&tile[xcw][vec * 8];
    *(bf16x8*)(orow + (size_t)(xcw + 1) * 512 + ci0 + vec * 8) = v;
    __syncthreads();
  }
}

// ---- kernel 3b: zero only the halo of xpad (replaces 19MB memset) ----
__global__ __launch_bounds__(256) void halo_zero_kernel(
    __hip_bfloat16* __restrict__ xpad) {
  const int sb = blockIdx.x;           // b*132 + site
  const int b = sb / 132, s = sb - b * 132;
  int y, x;
  if (s < 34)       { y = 0;        x = s; }
  else if (s < 68)  { y = 33;       x = s - 34; }
  else if (s < 100) { y = s - 67;   x = 0; }
  else              { y = s - 99;   x = 33; }
  unsigned* p = (unsigned*)(xpad + (size_t)((b * 34 + y) * 34 + x) * 512);
  p[threadIdx.x] = 0u;   // 256 x 4B = 512 bf16
}

// ---- kernel 4: implicit-GEMM conv, superset-B, A-dbuf, 2 blocks/CU ----
// LDS (77824B dyn): A bufs 2x16KB at 0; B superset 45056B at 32768
// ([344 rows][64 ci] of 128B; rows = yl*34+xl over the 10x34 xpad slice).
// XOR swizzle byte^=((row&7)<<4) on staging source chunk + ds_read (rule 21).
__global__ __launch_bounds__(256, 2) void conv_gemm_kernel(
    const __hip_bfloat16* __restrict__ wB3,   // [512][72][64]
    const __hip_bfloat16* __restrict__ xpad,  // [16][34][34][512]
    const float* __restrict__ rsig,           // [16][512]
    float* __restrict__ out,                  // f32 out (fallback, z=0)
    __hip_bfloat16* __restrict__ p0,          // bf16 partial z=0 (or null)
    __hip_bfloat16* __restrict__ p1) {        // bf16 partial z=1
  extern __shared__ __attribute__((aligned(16))) char ldsc[];

  const int tid = threadIdx.x;
  const int wv = tid >> 6, lane = tid & 63, l15 = lane & 15;
  const int bo0 = blockIdx.y << 7;        // cout block (128)
  const int bp0 = blockIdx.x << 8;        // pixel block (256)
  const int z = blockIdx.z;               // ci-half: groups z*4 .. z*4+3
  const int bimg = blockIdx.x >> 2;
  const int y0 = (blockIdx.x & 3) << 3;   // first output row (8 rows/block)
  const int wr = wv >> 1, wc = wv & 1;

  // A staging source offsets (pre-swizzled chunk; rule 21). + ktg*64 per tile.
  int gA[4];
#pragma unroll
  for (int r = 0; r < 4; ++r) {
    const int c = r * 256 + tid, row = c >> 3, sc = (c & 7) ^ (row & 7);
    gA[r] = (bo0 + row) * KTOT + sc * 8;
  }
  // B superset staging source offsets; + (z*4+g)*64 per group.
  int gBs[11];
#pragma unroll
  for (int r = 0; r < 11; ++r) {
    const int u = r * 256 + tid;
    int R = u >> 3; if (R > 339) R = 339;          // pad units -> clamp
    const int c = u & 7, sc = c ^ (R & 7);
    const int yl = R / 34, xl = R - yl * 34;
    gBs[r] = ((bimg * 34 + y0 + yl) * 34 + xl) * 512 + sc * 8;
  }
  // B-row base per n-frag: R = Rb[ni] + ty*34 + tx
  int Rb[8];
#pragma unroll
  for (int ni = 0; ni < 8; ++ni) {
    const int p = (wc << 7) + (ni << 4) + l15;
    Rb[ni] = (p >> 5) * 34 + (p & 31);
  }

  auto stageA = [&](int kt_next, int ktg_next) {
    char* dst = ldsc + (kt_next & 1) * 16384;
#pragma unroll
    for (int r = 0; r < 4; ++r)
      gload_lds16(wB3 + (size_t)(gA[r] + (ktg_next << 6)),
                  dst + (r * 256 + tid) * 16);
  };
  auto stageB = [&](int gg) {
    const int cio = ((z << 2) + gg) << 6;
    char* dst = ldsc + 32768;
#pragma unroll
    for (int r = 0; r < 11; ++r)
      gload_lds16(xpad + (size_t)(gBs[r] + cio), dst + (r * 256 + tid) * 16);
  };

  f32x4 acc[4][8];
#pragma unroll
  for (int mi = 0; mi < 4; ++mi)
#pragma unroll
    for (int ni = 0; ni < 8; ++ni) acc[mi][ni] = f32x4{0.f, 0.f, 0.f, 0.f};

  const int kb0 = (lane >> 4) << 4;

  // Prologue: B superset(group 0) + A tile 0; drain; barrier.
  stageB(0);
  stageA(0, z * 36);
  WAITV0();
  BAR();

#pragma unroll 1
  for (int g = 0; g < 4; ++g) {
#pragma unroll 1
    for (int tap = 0; tap < 9; ++tap) {
      const int kt = g * 9 + tap;
      if (kt < 35) stageA(kt + 1, z * 36 + kt + 1);   // buf[(kt+1)&1]: safe,
                                                      // last read at kt-1
      const char* bufA = ldsc + (kt & 1) * 16384;
      const char* bufB = ldsc + 32768;
      const int ty = (tap * 11) >> 5;       // tap/3
      const int tapoff = tap + 31 * ty;     // ty*34 + tx

      bf16x8 af[4][2];
#pragma unroll
      for (int mi = 0; mi < 4; ++mi) {
        const int row = (wr << 6) + (mi << 4) + l15;
        const int swz = (row & 7) << 4;
        af[mi][0] = *(const bf16x8*)(bufA + row * 128 + (kb0 ^ swz));
        af[mi][1] = *(const bf16x8*)(bufA + row * 128 + ((64 | kb0) ^ swz));
      }
      // k-half 0
      {
        bf16x8 bv[8];
#pragma unroll
        for (int ni = 0; ni < 8; ++ni) {
          const int R = Rb[ni] + tapoff;
          bv[ni] = *(const bf16x8*)(bufB + R * 128 + (kb0 ^ ((R & 7) << 4)));
        }
        __builtin_amdgcn_s_setprio(1);
#pragma unroll
        for (int mi = 0; mi < 4; ++mi)
#pragma unroll
          for (int ni = 0; ni < 8; ++ni)
            acc[mi][ni] = __builtin_amdgcn_mfma_f32_16x16x32_bf16(
                af[mi][0], bv[ni], acc[mi][ni], 0, 0, 0);
        __builtin_amdgcn_s_setprio(0);
      }
      // k-half 1 (last B reads of this tile happen here)
      {
        bf16x8 bv[8];
#pragma unroll
        for (int ni = 0; ni < 8; ++ni) {
          const int R = Rb[ni] + tapoff;
          bv[ni] = *(const bf16x8*)(bufB + R * 128 +
                                    ((64 | kb0) ^ ((R & 7) << 4)));
        }
        // Group edge: all waves' B reads done -> overwrite superset while
        // tap-8's remaining MFMAs (register-only) cover the DMA.
        if (tap == 8 && g < 3) { BAR(); stageB(g + 1); }
        __builtin_amdgcn_s_setprio(1);
#pragma unroll
        for (int mi = 0; mi < 4; ++mi)
#pragma unroll
          for (int ni = 0; ni < 8; ++ni)
            acc[mi][ni] = __builtin_amdgcn_mfma_f32_16x16x32_bf16(
                af[mi][1], bv[ni], acc[mi][ni], 0, 0, 0);
        __builtin_amdgcn_s_setprio(0);
      }
      WAITV0();   // drain A(kt+1) [+ B(g+1) at group edge]
      BAR();
    }
  }

  // Epilogue: scale by rsig; bf16 partial per z (f32 fallback if p0==null).
  // C/D: col(=p)=lane&15, row(=o)=(lane>>4)*4+r
  __hip_bfloat16* pz = z ? p1 : p0;
  const bool f32path = (p0 == nullptr) && (z == 0);
#pragma unroll
  for (int mi = 0; mi < 4; ++mi) {
    const int o = bo0 + (wr << 6) + (mi << 4) + ((lane >> 4) << 2);
    const f32x4 rs = *(const f32x4*)(rsig + (bimg << 9) + o);
#pragma unroll
    for (int ni = 0; ni < 8; ++ni) {
      const int p = bp0 + (wc << 7) + (ni << 4) + l15;
      const int prem = p & 1023;
#pragma unroll
      for (int r = 0; r < 4; ++r) {
        const float v = acc[mi][ni][r] * rs[r];
        const size_t oidx = ((size_t)((bimg << 9) + o + r)) * 1024 + prem;
        if (f32path) out[oidx] = v;
        else pz[oidx] = __float2bfloat16(v);
      }
    }
  }
}

// ---- kernel 5a: merge out = p0 + p1 ----
__global__ __launch_bounds__(256) void merge2_kernel(
    float* __restrict__ out, const __hip_bfloat16* __restrict__ p0,
    const __hip_bfloat16* __restrict__ p1) {
  const size_t i = (size_t)blockIdx.x * 256 + threadIdx.x;
  const bf16x8 a = ((const bf16x8*)p0)[i];
  const bf16x8 b = ((const bf16x8*)p1)[i];
  f32x4 o0, o1;
#pragma unroll
  for (int j = 0; j < 4; ++j) {
    o0[j] = bf16bits_to_f32(a[j]) + bf16bits_to_f32(b[j]);
    o1[j] = bf16bits_to_f32(a[4 + j]) + bf16bits_to_f32(b[4 + j]);
  }
  ((f32x4*)out)[2 * i] = o0;
  ((f32x4*)out)[2 * i + 1] = o1;
}

// ---- kernel 5b: fallback merge out += p1 ----
__global__ __launch_bounds__(256) void merge1_kernel(
    float* __restrict__ out, const __hip_bfloat16* __restrict__ p1) {
  const size_t i = (size_t)blockIdx.x * 256 + threadIdx.x;
  f32x4* o4 = (f32x4*)out + 2 * i;
  f32x4 a = o4[0], b = o4[1];
  const bf16x8 pv = ((const bf16x8*)p1)[i];
#pragma unroll
  for (int j = 0; j < 4; ++j) {
    a[j] += bf16bits_to_f32(pv[j]);
    b[j] += bf16bits_to_f32(pv[4 + j]);
  }
  o4[0] = a;
  o4[1] = b;
}

extern "C" void kernel_launch(void* const* d_in, const int* in_sizes, int n_in,
                              void* d_out, int out_size, void* d_ws,
                              size_t ws_size, hipStream_t stream) {
  const float* x = (const float*)d_in[0];   // [16,512,32,32]
  const float* s = (const float*)d_in[1];   // [16,512]
  const float* w = (const float*)d_in[2];   // [512,512,3,3]
  float* out = (float*)d_out;               // [16,512,32,32] f32

  char* ws = (char*)d_ws;
  const size_t xpad_bytes = (size_t)NB * 34 * 34 * 512 * 2;  // 18,939,904
  const size_t wB_bytes = (size_t)COUT * KTOT * 2;           //  4,718,592
  const size_t wsq_bytes = (size_t)COUT * CIN * 4;           //  1,048,576
  const size_t rsig_bytes = (size_t)NB * COUT * 4;           //     32,768
  const size_t part_bytes = (size_t)NPIX * COUT * 2;         // 16,777,216
  __hip_bfloat16* xpad = (__hip_bfloat16*)ws;
  __hip_bfloat16* wB3 = (__hip_bfloat16*)(ws + xpad_bytes);
  float* wsq = (float*)(ws + xpad_bytes + wB_bytes);
  float* rsig = (float*)(ws + xpad_bytes + wB_bytes + wsq_bytes);
  char* pbase = ws + xpad_bytes + wB_bytes + wsq_bytes + rsig_bytes;
  __hip_bfloat16* p1 = (__hip_bfloat16*)pbase;
  __hip_bfloat16* p0 = (__hip_bfloat16*)(pbase + part_bytes);
  const bool two_partials =
      ws_size >= (xpad_bytes + wB_bytes + wsq_bytes + rsig_bytes +
                  2 * part_bytes);

  const int lds_bytes = 77824;   // A 2x16KB + B 45056
  hipFuncSetAttribute((const void*)conv_gemm_kernel,
                      hipFuncAttributeMaxDynamicSharedMemorySize, lds_bytes);

  halo_zero_kernel<<<NB * 132, 256, 0, stream>>>(xpad);
  pack_w_kernel<<<(COUT * CIN) / 256, 256, 0, stream>>>(w, wB3, wsq);
  modulate_kernel<<<NB * 32, 256, 0, stream>>>(x, s, xpad);
  calc_rsig_kernel<<<(NB * COUT) / 4, 256, 0, stream>>>(s, wsq, rsig);
  conv_gemm_kernel<<<dim3(NPIX / 256, COUT / 128, 2), 256, lds_bytes, stream>>>(
      wB3, xpad, rsig, out, two_partials ? p0 : nullptr, p1);
  const int mblocks = (NPIX * COUT / 8) / 256;   // 4096
  if (two_partials)
    merge2_kernel<<<mblocks, 256, 0, stream>>>(out, p0, p1);
  else
    merge1_kernel<<<mblocks, 256, 0, stream>>>(out, p1);
}